// Round 2
// baseline (99.278 us; speedup 1.0000x reference)
//
#include <hip/hip_runtime.h>
#include <math.h>

#define B 1024
#define O 256
#define D 1024
#define ALPHA 0.005f

#define BPB 8            // b rows per block
#define DS  8            // D splits (blockIdx.y)
#define DCH (D / DS)     // 128 d per block
#define CH  4            // d per chunk = one float4 of c
#define NCH (DCH / CH)   // 32 chunks

// Kernel 0: transpose c[O][D] -> ct[D/4][O] (float4 elements)
// block = one d4-row group, tid = o  -> writes coalesced.
__global__ __launch_bounds__(256) void transpose_c(const float* __restrict__ c,
                                                   float4* __restrict__ ct)
{
    const int o  = threadIdx.x;         // 0..255
    const int d4 = blockIdx.x;          // 0..D/4-1
    const float* src = c + (size_t)o * D + d4 * 4;
    ct[(size_t)d4 * O + o] = make_float4(src[0], src[1], src[2], src[3]);
}

// Kernel 1: partial sums over a D-slice.
// lane -> centroid o; blockIdx.x -> 8 b rows; blockIdx.y -> d-slice.
// x addresses depend only on blockIdx + constants -> wave-uniform -> the
// compiler emits s_load into SGPRs; VALU consumes x as the scalar operand
// (v_sub_f32 d, s_x, v_c). Only c streams through VMEM, prefetch distance 2.
__global__ __launch_bounds__(256, 4) void dist_part(const float* __restrict__ x,
                                                    const float4* __restrict__ ct,
                                                    float* __restrict__ s1p,
                                                    float* __restrict__ s2p)
{
    const int o  = threadIdx.x;               // centroid index
    const int b0 = blockIdx.x * BPB;          // first b row
    const int ds = blockIdx.y;                // d-slice
    const int d4base = ds * (DCH / 4);        // base float4-index into ct rows

    const float4* cts = ct + (size_t)d4base * O + o;   // step O per d4 row
    const float*  xs  = x + (size_t)b0 * D + ds * DCH; // wave-uniform base

    float s1[BPB], s2[BPB];
    #pragma unroll
    for (int i = 0; i < BPB; ++i) { s1[i] = 0.f; s2[i] = 0.f; }

#define LOADC(CHIDX) cts[(size_t)(CHIDX) * O]

#define COMPUTE(CV, CHIDX)                                                  \
    { _Pragma("unroll")                                                     \
      for (int bi = 0; bi < BPB; ++bi) {                                    \
          const float4 xv = *(const float4*)(xs + (size_t)bi * D + (CHIDX) * CH); \
          const float d0 = xv.x - CV.x, d1 = xv.y - CV.y,                   \
                      d2 = xv.z - CV.z, d3 = xv.w - CV.w;                   \
          s1[bi] += __builtin_fabsf(d0); s2[bi] = __builtin_fmaf(d0, d0, s2[bi]); \
          s1[bi] += __builtin_fabsf(d1); s2[bi] = __builtin_fmaf(d1, d1, s2[bi]); \
          s1[bi] += __builtin_fabsf(d2); s2[bi] = __builtin_fmaf(d2, d2, s2[bi]); \
          s1[bi] += __builtin_fabsf(d3); s2[bi] = __builtin_fmaf(d3, d3, s2[bi]); \
      } }

    // c double-buffered at prefetch distance 2 chunks, 4-chunk unrolled body
    // (no register rotation moves).
    float4 cA = LOADC(0);
    float4 cB = LOADC(1);
    for (int ch = 0; ch < NCH; ch += 4) {
        float4 cC = LOADC(ch + 2 < NCH ? ch + 2 : NCH - 1);
        float4 cD = LOADC(ch + 3 < NCH ? ch + 3 : NCH - 1);
        COMPUTE(cA, ch)
        COMPUTE(cB, ch + 1)
        cA = LOADC(ch + 4 < NCH ? ch + 4 : NCH - 1);
        cB = LOADC(ch + 5 < NCH ? ch + 5 : NCH - 1);
        COMPUTE(cC, ch + 2)
        COMPUTE(cD, ch + 3)
    }
#undef LOADC
#undef COMPUTE

    #pragma unroll
    for (int i = 0; i < BPB; ++i) {
        const size_t idx = ((size_t)ds * B + (b0 + i)) * O + o;
        s1p[idx] = s1[i];
        s2p[idx] = s2[i];
    }
}

// Kernel 2: combine D-slices, sqrt + temperature + alpha row-correction.
__global__ __launch_bounds__(256) void combine_kernel(const float* __restrict__ s1p,
                                                      const float* __restrict__ s2p,
                                                      float* __restrict__ out)
{
    const int b = blockIdx.x;
    const int o = threadIdx.x;

    float a1 = 0.f, a2 = 0.f;
    #pragma unroll
    for (int ds = 0; ds < DS; ++ds) {
        const size_t idx = ((size_t)ds * B + b) * O + o;
        a1 += s1p[idx];
        a2 += s2p[idx];
    }
    const float v = a1 + 0.5f * __builtin_sqrtf(a2);

    float t = v;
    #pragma unroll
    for (int off = 32; off >= 1; off >>= 1)
        t += __shfl_down(t, off, 64);

    __shared__ float ws[4];
    if ((o & 63) == 0) ws[o >> 6] = t;
    __syncthreads();
    const float S = ws[0] + ws[1] + ws[2] + ws[3];

    out[(size_t)b * O + o] = ALPHA * S - (1.0f + ALPHA) * v;
}

extern "C" void kernel_launch(void* const* d_in, const int* in_sizes, int n_in,
                              void* d_out, int out_size, void* d_ws, size_t ws_size,
                              hipStream_t stream) {
    const float* x = (const float*)d_in[0];   // [B, D]
    const float* c = (const float*)d_in[1];   // [O, D]
    float* out = (float*)d_out;               // [B, O]

    float*  s1p = (float*)d_ws;                          // [DS, B, O] = 8 MB
    float*  s2p = s1p + (size_t)DS * B * O;              // [DS, B, O] = 8 MB
    float4* ct  = (float4*)(s2p + (size_t)DS * B * O);   // [D/4, O]   = 1 MB

    transpose_c<<<D / 4, O, 0, stream>>>(c, ct);

    dim3 grid(B / BPB, DS);                   // (128, 8) = 1024 blocks
    dist_part<<<grid, 256, 0, stream>>>(x, ct, s1p, s2p);
    combine_kernel<<<B, 256, 0, stream>>>(s1p, s2p, out);
}

// Round 3
// 98.035 us; speedup vs baseline: 1.0127x; 1.0127x over previous
//
#include <hip/hip_runtime.h>
#include <math.h>

#define B 1024
#define O 256
#define D 1024
#define ALPHA 0.005f

#define OT 8             // o's per thread (register tile)
#define DS 8             // D splits (blockIdx.z)
#define DCH (D / DS)     // 128 d per block
#define TT 64            // transpose tile

// Kernel 0: LDS-tiled transpose, coalesced on BOTH sides.
// blocks 0..255   : x[1024][1024] -> xt[1024][1024]   (16x16 tiles)
// blocks 256..319 : c[256][1024]  -> ct[1024][256]    (4x16 tiles)
__global__ __launch_bounds__(256) void prep_transpose(const float* __restrict__ x,
                                                      const float* __restrict__ c,
                                                      float* __restrict__ xt,
                                                      float* __restrict__ ct)
{
    __shared__ float tile[TT][TT + 1];

    int bid = blockIdx.x;
    const float* src;
    float* dst;
    int R, r0, c0;
    if (bid < 256) {
        src = x;  dst = xt;  R = B;
        r0 = (bid / 16) * TT;  c0 = (bid % 16) * TT;
    } else {
        bid -= 256;
        src = c;  dst = ct;  R = O;
        r0 = (bid / 16) * TT;  c0 = (bid % 16) * TT;
    }

    const int tr = threadIdx.x / 16;   // 0..15
    const int tc = threadIdx.x % 16;   // 0..15, x4 floats

    #pragma unroll
    for (int k = 0; k < TT; k += 16) {
        const float4 v = *(const float4*)(src + (size_t)(r0 + tr + k) * D + c0 + tc * 4);
        tile[tr + k][tc * 4 + 0] = v.x;
        tile[tr + k][tc * 4 + 1] = v.y;
        tile[tr + k][tc * 4 + 2] = v.z;
        tile[tr + k][tc * 4 + 3] = v.w;
    }
    __syncthreads();
    #pragma unroll
    for (int k = 0; k < TT; k += 16) {
        const float4 v = make_float4(tile[tc * 4 + 0][tr + k],
                                     tile[tc * 4 + 1][tr + k],
                                     tile[tc * 4 + 2][tr + k],
                                     tile[tc * 4 + 3][tr + k]);
        *(float4*)(dst + (size_t)(c0 + tr + k) * R + r0 + tc * 4) = v;
    }
}

// Kernel 1: partial sums over a D-slice.
// lane -> b (coalesced x reads from xt); register tile -> 8 o's whose c
// values come from wave-uniform addresses (scalar-pipe s_load candidates).
__global__ __launch_bounds__(256, 4) void dist_part(const float* __restrict__ xt,
                                                    const float* __restrict__ ct,
                                                    float* __restrict__ s1p,
                                                    float* __restrict__ s2p)
{
    const int b  = blockIdx.x * 256 + threadIdx.x;   // B/256 = 4
    const int o0 = blockIdx.y * OT;                  // O/OT  = 32
    const int ds = blockIdx.z;                       // DS    = 8
    const int d0 = ds * DCH;

    const float* xp = xt + (size_t)d0 * B + b;       // per-lane, step B per d
    const float* cp = ct + (size_t)d0 * O + o0;      // wave-uniform, step O per d

    float s1[OT], s2[OT];
    #pragma unroll
    for (int j = 0; j < OT; ++j) { s1[j] = 0.f; s2[j] = 0.f; }

    #pragma unroll 4
    for (int dd = 0; dd < DCH; ++dd) {
        const float xv = xp[(size_t)dd * B];
        #pragma unroll
        for (int j = 0; j < OT; ++j) {
            const float cv = cp[(size_t)dd * O + j];
            const float df = xv - cv;
            s1[j] += __builtin_fabsf(df);
            s2[j]  = __builtin_fmaf(df, df, s2[j]);
        }
    }

    // partials [DS][B][O]; per thread 2x16B contiguous per array
    const size_t base = ((size_t)ds * B + b) * O + o0;
    *(float4*)(s1p + base)     = make_float4(s1[0], s1[1], s1[2], s1[3]);
    *(float4*)(s1p + base + 4) = make_float4(s1[4], s1[5], s1[6], s1[7]);
    *(float4*)(s2p + base)     = make_float4(s2[0], s2[1], s2[2], s2[3]);
    *(float4*)(s2p + base + 4) = make_float4(s2[4], s2[5], s2[6], s2[7]);
}

// Kernel 2: combine D-slices, sqrt + temperature + alpha row-correction.
__global__ __launch_bounds__(256) void combine_kernel(const float* __restrict__ s1p,
                                                      const float* __restrict__ s2p,
                                                      float* __restrict__ out)
{
    const int b = blockIdx.x;
    const int o = threadIdx.x;

    float a1 = 0.f, a2 = 0.f;
    #pragma unroll
    for (int ds = 0; ds < DS; ++ds) {
        const size_t idx = ((size_t)ds * B + b) * O + o;
        a1 += s1p[idx];
        a2 += s2p[idx];
    }
    const float v = a1 + 0.5f * __builtin_sqrtf(a2);

    float t = v;
    #pragma unroll
    for (int off = 32; off >= 1; off >>= 1)
        t += __shfl_down(t, off, 64);

    __shared__ float ws[4];
    if ((o & 63) == 0) ws[o >> 6] = t;
    __syncthreads();
    const float S = ws[0] + ws[1] + ws[2] + ws[3];

    out[(size_t)b * O + o] = ALPHA * S - (1.0f + ALPHA) * v;
}

extern "C" void kernel_launch(void* const* d_in, const int* in_sizes, int n_in,
                              void* d_out, int out_size, void* d_ws, size_t ws_size,
                              hipStream_t stream) {
    const float* x = (const float*)d_in[0];   // [B, D]
    const float* c = (const float*)d_in[1];   // [O, D]
    float* out = (float*)d_out;               // [B, O]

    float* s1p = (float*)d_ws;                          // [DS, B, O] = 8 MB
    float* s2p = s1p + (size_t)DS * B * O;              // [DS, B, O] = 8 MB
    float* xt  = s2p + (size_t)DS * B * O;              // [D, B]     = 4 MB
    float* ct  = xt + (size_t)D * B;                    // [D, O]     = 1 MB

    prep_transpose<<<320, 256, 0, stream>>>(x, c, xt, ct);

    dim3 grid(B / 256, O / OT, DS);           // (4, 32, 8) = 1024 blocks
    dist_part<<<grid, 256, 0, stream>>>(xt, ct, s1p, s2p);
    combine_kernel<<<B, 256, 0, stream>>>(s1p, s2p, out);
}